// Round 4
// baseline (2256.380 us; speedup 1.0000x reference)
//
#include <hip/hip_runtime.h>
#include <hip/hip_bf16.h>

#define NN 100000
#define NE 1600000
#define SW 136   // padded stride (shorts) for [64][128] bf16 weight tiles
#define ST 68    // padded stride (shorts) for [16][64] bf16 link tiles

typedef __attribute__((ext_vector_type(8))) short bf16x8;
typedef __attribute__((ext_vector_type(4))) float f32x4;

__device__ __forceinline__ unsigned short f2bf(float f) {
    union { float f; unsigned int u; } v; v.f = f;
    unsigned int u = v.u + 0x7fff + ((v.u >> 16) & 1);
    return (unsigned short)(u >> 16);
}
__device__ __forceinline__ float bf2f(unsigned short h) {
    union { unsigned int u; float f; } v; v.u = ((unsigned int)h) << 16;
    return v.f;
}
__device__ __forceinline__ float silu_f(float v) {
    return v / (1.0f + __expf(-v));
}

// ---------------- CSR build ----------------
__global__ void hist_kernel(const int* __restrict__ dst, int* __restrict__ counts) {
    int i = blockIdx.x * 256 + threadIdx.x;
    if (i < NE) atomicAdd(&counts[dst[i]], 1);
}

// single block, 1024 threads: exclusive scan of counts -> rowptr, cursor
__global__ __launch_bounds__(1024) void scan_kernel(const int* __restrict__ counts,
                                                    int* __restrict__ rowptr,
                                                    int* __restrict__ cursor) {
    __shared__ int tsum[1024];
    const int T = 1024;
    int tid = threadIdx.x;
    const int per = (NN + T - 1) / T;
    int base = tid * per;
    int s = 0;
    for (int i = 0; i < per; ++i) {
        int idx = base + i;
        if (idx < NN) s += counts[idx];
    }
    tsum[tid] = s;
    __syncthreads();
    for (int off = 1; off < T; off <<= 1) {
        int v = tsum[tid];
        int add = (tid >= off) ? tsum[tid - off] : 0;
        __syncthreads();
        tsum[tid] = v + add;
        __syncthreads();
    }
    int run = (tid == 0) ? 0 : tsum[tid - 1];
    for (int i = 0; i < per; ++i) {
        int idx = base + i;
        if (idx < NN) {
            rowptr[idx] = run;
            cursor[idx] = run;
            run += counts[idx];
        }
    }
    if (tid == T - 1) rowptr[NN] = run;
}

__global__ void scatter_kernel(const int* __restrict__ src, const int* __restrict__ dst,
                               int* __restrict__ cursor, int* __restrict__ srcS) {
    int i = blockIdx.x * 256 + threadIdx.x;
    if (i < NE) {
        int pos = atomicAdd(&cursor[dst[i]], 1);
        srcS[pos] = src[i];
    }
}

// ---------------------------------------------------------------------------
// Edge kernel over CSR: one WAVE per dst node. msg_h accumulated in fp32
// registers across 16-edge chunks; ONE non-atomic store per node. No atomics.
// MFMA 16x16x32 bf16. A[m=l15][k=quad*8+j]; C/D: col=l15+16nt, row=quad*4+r
// ---------------------------------------------------------------------------
template <bool WRITE_X>
__global__ __launch_bounds__(256, 4) void edge2_kernel(
    const float* __restrict__ xcur,
    const unsigned short* __restrict__ hbf,
    const int* __restrict__ rowptr,
    const int* __restrict__ srcS,
    const float* __restrict__ ew1,   // [129,64]
    const float* __restrict__ eb1,
    const float* __restrict__ ew2,   // [64,64]
    const float* __restrict__ eb2,
    const float* __restrict__ cw1,   // [64,64]
    const float* __restrict__ cb1,
    const float* __restrict__ cw2,   // [64]
    unsigned short* __restrict__ h_nb,  // [N,64] bf16 out
    float* __restrict__ xout)           // [N,3] out (WRITE_X only)
{
    __shared__ __align__(16) unsigned short w1T[64 * SW];      // B^T GEMM1
    __shared__ __align__(16) unsigned short c1T[64 * ST];      // B^T GEMM3
    __shared__ __align__(16) unsigned short tAll[4 * 16 * ST]; // per-wave link buf
    __shared__ float eb1s[64], eb2s[64], cb1s[64], cw2s[64], w1l[64];

    const int tid  = threadIdx.x;
    const int wave = tid >> 6;
    const int lane = tid & 63;
    const int quad = lane >> 4;
    const int l15  = lane & 15;

    for (int i = tid; i < 64 * 128; i += 256) {
        int n = i & 63, k = i >> 6;
        w1T[n * SW + k] = f2bf(ew1[k * 64 + n]);
    }
    if (WRITE_X) {
        for (int i = tid; i < 64 * 64; i += 256) {
            int n = i & 63, k = i >> 6;
            c1T[n * ST + k] = f2bf(cw1[k * 64 + n]);
        }
    }
    if (tid < 64) {
        eb1s[tid] = eb1[tid]; eb2s[tid] = eb2[tid]; cb1s[tid] = cb1[tid];
        cw2s[tid] = cw2[tid]; w1l[tid] = ew1[128 * 64 + tid];
    }
    bf16x8 b2[2][4];
#pragma unroll
    for (int ks = 0; ks < 2; ++ks)
#pragma unroll
        for (int nt = 0; nt < 4; ++nt) {
#pragma unroll
            for (int j = 0; j < 8; ++j) {
                int k = ks * 32 + quad * 8 + j;
                ((unsigned short*)&b2[ks][nt])[j] = f2bf(ew2[k * 64 + nt * 16 + l15]);
            }
        }
    __syncthreads();   // only barrier

    unsigned short* tW = tAll + wave * 16 * ST;
    const int gw = blockIdx.x * 4 + wave;
    const int nw = gridDim.x * 4;

    for (int n = gw; n < NN; n += nw) {
        const int segS = rowptr[n], segE = rowptr[n + 1];
        const float xnx = xcur[n * 3 + 0], xny = xcur[n * 3 + 1], xnz = xcur[n * 3 + 2];
        const unsigned short* pn = hbf + (size_t)n * 64 + quad * 8;
        bf16x8 a2 = *(const bf16x8*)(pn);
        bf16x8 a3 = *(const bf16x8*)(pn + 32);

        float macc[4][4];
#pragma unroll
        for (int nt = 0; nt < 4; ++nt)
#pragma unroll
            for (int r = 0; r < 4; ++r) macc[nt][r] = 0.f;
        float xacc[4] = {0.f, 0.f, 0.f, 0.f};

        for (int cs = segS; cs < segE; cs += 16) {
            int s = n; float rad = 0.f, xdx = 0.f, xdy = 0.f, xdz = 0.f;
            if (lane < 16) {
                int e = cs + lane;
                if (e < segE) {
                    s = srcS[e];
                    float dx = xcur[s * 3 + 0] - xnx;
                    float dy = xcur[s * 3 + 1] - xny;
                    float dz = xcur[s * 3 + 2] - xnz;
                    rad = dx * dx + dy * dy + dz * dz;
                    float inv = 1.0f / (sqrtf(rad) + 1e-30f);
                    xdx = dx * inv; xdy = dy * inv; xdz = dz * inv;
                }
            }
            const int rowS = __shfl(s, l15);
            const unsigned short* ps = hbf + (size_t)rowS * 64 + quad * 8;
            bf16x8 a0 = *(const bf16x8*)(ps);
            bf16x8 a1 = *(const bf16x8*)(ps + 32);

            float radR[4]; float cxR[4], cyR[4], czR[4]; bool valR[4];
#pragma unroll
            for (int r = 0; r < 4; ++r) {
                int er = quad * 4 + r;
                radR[r] = __shfl(rad, er);
                valR[r] = (cs + er) < segE;
                if (WRITE_X) {
                    cxR[r] = __shfl(xdx, er);
                    cyR[r] = __shfl(xdy, er);
                    czR[r] = __shfl(xdz, er);
                }
            }

            // GEMM1: K=128 (cols 0..63 h[src], 64..127 h[dst])
            f32x4 acc[4];
#pragma unroll
            for (int nt = 0; nt < 4; ++nt) acc[nt] = (f32x4){0.f, 0.f, 0.f, 0.f};
            {
                const unsigned short* bBase = &w1T[l15 * SW + quad * 8];
#pragma unroll
                for (int nt = 0; nt < 4; ++nt) {
                    const unsigned short* bb = bBase + nt * 16 * SW;
                    acc[nt] = __builtin_amdgcn_mfma_f32_16x16x32_bf16(a0, *(const bf16x8*)(bb), acc[nt], 0, 0, 0);
                    acc[nt] = __builtin_amdgcn_mfma_f32_16x16x32_bf16(a1, *(const bf16x8*)(bb + 32), acc[nt], 0, 0, 0);
                    acc[nt] = __builtin_amdgcn_mfma_f32_16x16x32_bf16(a2, *(const bf16x8*)(bb + 64), acc[nt], 0, 0, 0);
                    acc[nt] = __builtin_amdgcn_mfma_f32_16x16x32_bf16(a3, *(const bf16x8*)(bb + 96), acc[nt], 0, 0, 0);
                }
            }
#pragma unroll
            for (int nt = 0; nt < 4; ++nt) {
                int col = nt * 16 + l15;
#pragma unroll
                for (int r = 0; r < 4; ++r) {
                    float v = acc[nt][r] + eb1s[col] + radR[r] * w1l[col];
                    tW[(quad * 4 + r) * ST + col] = f2bf(silu_f(v));
                }
            }
            // GEMM2: K=64
            f32x4 acc2[4];
#pragma unroll
            for (int nt = 0; nt < 4; ++nt) acc2[nt] = (f32x4){0.f, 0.f, 0.f, 0.f};
            {
                bf16x8 ax0 = *(const bf16x8*)&tW[l15 * ST + quad * 8];
                bf16x8 ax1 = *(const bf16x8*)&tW[l15 * ST + 32 + quad * 8];
#pragma unroll
                for (int nt = 0; nt < 4; ++nt) {
                    acc2[nt] = __builtin_amdgcn_mfma_f32_16x16x32_bf16(ax0, b2[0][nt], acc2[nt], 0, 0, 0);
                    acc2[nt] = __builtin_amdgcn_mfma_f32_16x16x32_bf16(ax1, b2[1][nt], acc2[nt], 0, 0, 0);
                }
            }
#pragma unroll
            for (int nt = 0; nt < 4; ++nt) {
                int col = nt * 16 + l15;
#pragma unroll
                for (int r = 0; r < 4; ++r) {
                    float v = silu_f(acc2[nt][r] + eb2s[col]);
                    if (valR[r]) macc[nt][r] += v;
                    if (WRITE_X) tW[(quad * 4 + r) * ST + col] = f2bf(v);
                }
            }
            if (WRITE_X) {
                // GEMM3: K=64
                f32x4 acc3[4];
#pragma unroll
                for (int nt = 0; nt < 4; ++nt) acc3[nt] = (f32x4){0.f, 0.f, 0.f, 0.f};
                {
                    bf16x8 ax0 = *(const bf16x8*)&tW[l15 * ST + quad * 8];
                    bf16x8 ax1 = *(const bf16x8*)&tW[l15 * ST + 32 + quad * 8];
                    const unsigned short* bBase = &c1T[l15 * ST + quad * 8];
#pragma unroll
                    for (int nt = 0; nt < 4; ++nt) {
                        const unsigned short* bb = bBase + nt * 16 * ST;
                        acc3[nt] = __builtin_amdgcn_mfma_f32_16x16x32_bf16(ax0, *(const bf16x8*)(bb), acc3[nt], 0, 0, 0);
                        acc3[nt] = __builtin_amdgcn_mfma_f32_16x16x32_bf16(ax1, *(const bf16x8*)(bb + 32), acc3[nt], 0, 0, 0);
                    }
                }
                float part_[4] = {0.f, 0.f, 0.f, 0.f};
#pragma unroll
                for (int nt = 0; nt < 4; ++nt) {
                    int col = nt * 16 + l15;
#pragma unroll
                    for (int r = 0; r < 4; ++r)
                        part_[r] += silu_f(acc3[nt][r] + cb1s[col]) * cw2s[col];
                }
#pragma unroll
                for (int r = 0; r < 4; ++r) {
                    float p = part_[r];
                    p += __shfl_xor(p, 1);
                    p += __shfl_xor(p, 2);
                    p += __shfl_xor(p, 4);
                    p += __shfl_xor(p, 8);
                    if (valR[r]) {
                        float comp = (l15 == 0) ? cxR[r] : (l15 == 1) ? cyR[r] : czR[r];
                        xacc[r] += p * comp;   // meaningful for l15<3 only
                    }
                }
            }
        }
        // reduce msg accumulator over rows (r in-lane, quads via shfl) and store
#pragma unroll
        for (int nt = 0; nt < 4; ++nt) {
            float mm = macc[nt][0] + macc[nt][1] + macc[nt][2] + macc[nt][3];
            mm += __shfl_xor(mm, 16);
            mm += __shfl_xor(mm, 32);
            if (quad == 0) h_nb[(size_t)n * 64 + nt * 16 + l15] = f2bf(mm);
        }
        if (WRITE_X) {
            float xa = xacc[0] + xacc[1] + xacc[2] + xacc[3];
            xa += __shfl_xor(xa, 16);
            xa += __shfl_xor(xa, 32);
            if (quad == 0 && l15 < 3) {
                float d = fmaxf((float)(segE - segS), 1.0f);
                float base = (l15 == 0) ? xnx : (l15 == 1) ? xny : xnz;
                xout[n * 3 + l15] = base + xa / d;
            }
        }
    }
}

// ---------------------------------------------------------------------------
// Node kernel: h_new = silu([h|h_nb]@NW1+nb1)@NW2+nb2 -> gelu -> LayerNorm.
// DO_HEAD: fuse final out = y@out_w+out_b (skip hbf store).
// ---------------------------------------------------------------------------
template <bool DO_HEAD>
__global__ __launch_bounds__(256, 4) void node_kernel(
    unsigned short* hbf,
    const unsigned short* __restrict__ h_nb,   // [N,64] bf16
    const float* __restrict__ nw1,
    const float* __restrict__ nb1,
    const float* __restrict__ nw2,
    const float* __restrict__ nb2,
    const float* __restrict__ ln_g,
    const float* __restrict__ ln_b,
    const float* __restrict__ out_w,  // [64,32]
    const float* __restrict__ out_b,  // [32]
    float* __restrict__ out)          // [N,32]
{
    __shared__ __align__(16) unsigned short w1T[64 * SW];
    __shared__ __align__(16) unsigned short tAll[4 * 16 * ST];
    __shared__ float nb1s[64], nb2s[64], gs[64], bs[64], obs[32];

    const int tid  = threadIdx.x;
    const int wave = tid >> 6;
    const int lane = tid & 63;
    const int quad = lane >> 4;
    const int l15  = lane & 15;

    for (int i = tid; i < 64 * 128; i += 256) {
        int n = i & 63, k = i >> 6;
        w1T[n * SW + k] = f2bf(nw1[k * 64 + n]);
    }
    if (tid < 64) {
        nb1s[tid] = nb1[tid]; nb2s[tid] = nb2[tid];
        gs[tid] = ln_g[tid]; bs[tid] = ln_b[tid];
        if (DO_HEAD && tid < 32) obs[tid] = out_b[tid];
    }
    bf16x8 b2[2][4];
#pragma unroll
    for (int ks = 0; ks < 2; ++ks)
#pragma unroll
        for (int nt = 0; nt < 4; ++nt) {
#pragma unroll
            for (int j = 0; j < 8; ++j) {
                int k = ks * 32 + quad * 8 + j;
                ((unsigned short*)&b2[ks][nt])[j] = f2bf(nw2[k * 64 + nt * 16 + l15]);
            }
        }
    bf16x8 b3[2][2];
    if (DO_HEAD) {
#pragma unroll
        for (int ks = 0; ks < 2; ++ks)
#pragma unroll
            for (int nt = 0; nt < 2; ++nt) {
#pragma unroll
                for (int j = 0; j < 8; ++j) {
                    int k = ks * 32 + quad * 8 + j;
                    ((unsigned short*)&b3[ks][nt])[j] = f2bf(out_w[k * 32 + nt * 16 + l15]);
                }
            }
    }
    __syncthreads();

    unsigned short* tW = tAll + wave * 16 * ST;

    for (int t = blockIdx.x * 4 + wave; t < NN / 16; t += gridDim.x * 4) {
        const int n0 = t * 16;
        const int myRow = n0 + l15;
        const unsigned short* ph = hbf + (size_t)myRow * 64 + quad * 8;
        bf16x8 a0 = *(const bf16x8*)(ph);
        bf16x8 a1 = *(const bf16x8*)(ph + 32);
        const unsigned short* pb = h_nb + (size_t)myRow * 64 + quad * 8;
        bf16x8 a2 = *(const bf16x8*)(pb);
        bf16x8 a3 = *(const bf16x8*)(pb + 32);

        f32x4 acc[4];
#pragma unroll
        for (int nt = 0; nt < 4; ++nt) acc[nt] = (f32x4){0.f, 0.f, 0.f, 0.f};
        {
            const unsigned short* bBase = &w1T[l15 * SW + quad * 8];
#pragma unroll
            for (int nt = 0; nt < 4; ++nt) {
                const unsigned short* bb = bBase + nt * 16 * SW;
                acc[nt] = __builtin_amdgcn_mfma_f32_16x16x32_bf16(a0, *(const bf16x8*)(bb), acc[nt], 0, 0, 0);
                acc[nt] = __builtin_amdgcn_mfma_f32_16x16x32_bf16(a1, *(const bf16x8*)(bb + 32), acc[nt], 0, 0, 0);
                acc[nt] = __builtin_amdgcn_mfma_f32_16x16x32_bf16(a2, *(const bf16x8*)(bb + 64), acc[nt], 0, 0, 0);
                acc[nt] = __builtin_amdgcn_mfma_f32_16x16x32_bf16(a3, *(const bf16x8*)(bb + 96), acc[nt], 0, 0, 0);
            }
        }
#pragma unroll
        for (int nt = 0; nt < 4; ++nt) {
            int col = nt * 16 + l15;
#pragma unroll
            for (int r = 0; r < 4; ++r) {
                float v = acc[nt][r] + nb1s[col];
                tW[(quad * 4 + r) * ST + col] = f2bf(silu_f(v));
            }
        }
        f32x4 acc2[4];
#pragma unroll
        for (int nt = 0; nt < 4; ++nt) acc2[nt] = (f32x4){0.f, 0.f, 0.f, 0.f};
        {
            bf16x8 ax0 = *(const bf16x8*)&tW[l15 * ST + quad * 8];
            bf16x8 ax1 = *(const bf16x8*)&tW[l15 * ST + 32 + quad * 8];
#pragma unroll
            for (int nt = 0; nt < 4; ++nt) {
                acc2[nt] = __builtin_amdgcn_mfma_f32_16x16x32_bf16(ax0, b2[0][nt], acc2[nt], 0, 0, 0);
                acc2[nt] = __builtin_amdgcn_mfma_f32_16x16x32_bf16(ax1, b2[1][nt], acc2[nt], 0, 0, 0);
            }
        }
        float vals[4][4];
        float sum[4] = {0.f, 0.f, 0.f, 0.f}, ss[4] = {0.f, 0.f, 0.f, 0.f};
#pragma unroll
        for (int nt = 0; nt < 4; ++nt) {
            int col = nt * 16 + l15;
#pragma unroll
            for (int r = 0; r < 4; ++r) {
                float v = acc2[nt][r] + nb2s[col];
                float g = 0.5f * v * (1.0f + erff(v * 0.70710678118654752f));
                vals[nt][r] = g;
                sum[r] += g;
                ss[r] += g * g;
            }
        }
#pragma unroll
        for (int r = 0; r < 4; ++r) {
            float s1 = sum[r], s2 = ss[r];
            s1 += __shfl_xor(s1, 1); s2 += __shfl_xor(s2, 1);
            s1 += __shfl_xor(s1, 2); s2 += __shfl_xor(s2, 2);
            s1 += __shfl_xor(s1, 4); s2 += __shfl_xor(s2, 4);
            s1 += __shfl_xor(s1, 8); s2 += __shfl_xor(s2, 8);
            sum[r] = s1; ss[r] = s2;
        }
#pragma unroll
        for (int r = 0; r < 4; ++r) {
            float mean = sum[r] * (1.0f / 64.0f);
            float var  = ss[r] * (1.0f / 64.0f) - mean * mean;
            float rstd = rsqrtf(var + 1e-5f);
            int n = n0 + quad * 4 + r;
#pragma unroll
            for (int nt = 0; nt < 4; ++nt) {
                int col = nt * 16 + l15;
                float y = (vals[nt][r] - mean) * rstd * gs[col] + bs[col];
                if (DO_HEAD) tW[(quad * 4 + r) * ST + col] = f2bf(y);
                else hbf[(size_t)n * 64 + col] = f2bf(y);
            }
        }
        if (DO_HEAD) {
            f32x4 accH[2];
#pragma unroll
            for (int nt = 0; nt < 2; ++nt) accH[nt] = (f32x4){0.f, 0.f, 0.f, 0.f};
            bf16x8 ax0 = *(const bf16x8*)&tW[l15 * ST + quad * 8];
            bf16x8 ax1 = *(const bf16x8*)&tW[l15 * ST + 32 + quad * 8];
#pragma unroll
            for (int nt = 0; nt < 2; ++nt) {
                accH[nt] = __builtin_amdgcn_mfma_f32_16x16x32_bf16(ax0, b3[0][nt], accH[nt], 0, 0, 0);
                accH[nt] = __builtin_amdgcn_mfma_f32_16x16x32_bf16(ax1, b3[1][nt], accH[nt], 0, 0, 0);
            }
#pragma unroll
            for (int nt = 0; nt < 2; ++nt) {
                int col = nt * 16 + l15;
#pragma unroll
                for (int r = 0; r < 4; ++r)
                    out[(size_t)(n0 + quad * 4 + r) * 32 + col] = accH[nt][r] + obs[col];
            }
        }
    }
}

__global__ void init_h(const float* __restrict__ nf, unsigned short* __restrict__ hbf) {
    int i = blockIdx.x * 256 + threadIdx.x;
    if (i < NN * 64) hbf[i] = f2bf(nf[i]);
}
__global__ void init_x(const float* __restrict__ xyz, float* __restrict__ xcur) {
    int i = blockIdx.x * 256 + threadIdx.x;
    if (i < NN * 3) xcur[i] = xyz[i];
}

extern "C" void kernel_launch(void* const* d_in, const int* in_sizes, int n_in,
                              void* d_out, int out_size, void* d_ws, size_t ws_size,
                              hipStream_t stream)
{
    const float* node_feat = (const float*)d_in[0];
    const float* xyz   = (const float*)d_in[1];
    const int*   src   = (const int*)d_in[2];
    const int*   dst   = (const int*)d_in[3];
    const float* ew1   = (const float*)d_in[4];
    const float* eb1   = (const float*)d_in[5];
    const float* ew2   = (const float*)d_in[6];
    const float* eb2   = (const float*)d_in[7];
    const float* cw1   = (const float*)d_in[8];
    const float* cb1   = (const float*)d_in[9];
    const float* cw2   = (const float*)d_in[10];
    const float* nw1   = (const float*)d_in[11];
    const float* nb1   = (const float*)d_in[12];
    const float* nw2   = (const float*)d_in[13];
    const float* nb2   = (const float*)d_in[14];
    const float* ln_g  = (const float*)d_in[15];
    const float* ln_b  = (const float*)d_in[16];
    const float* out_w = (const float*)d_in[17];
    const float* out_b = (const float*)d_in[18];
    float* out = (float*)d_out;

    char* ws = (char*)d_ws;
    unsigned short* h_nb = (unsigned short*)ws;  ws += (size_t)NN * 64 * 2;
    unsigned short* hbf  = (unsigned short*)ws;  ws += (size_t)NN * 64 * 2;
    float* xA    = (float*)ws;                   ws += (size_t)NN * 3 * 4;
    float* xB    = (float*)ws;                   ws += (size_t)NN * 3 * 4;
    int* rowptr  = (int*)ws;                     ws += (size_t)(NN + 1) * 4;
    int* counts  = (int*)ws;                     ws += (size_t)NN * 4;   // reused as cursor
    int* srcS    = (int*)ws;                     ws += (size_t)NE * 4;

    hipMemsetAsync(counts, 0, (size_t)NN * 4, stream);
    init_h<<<(NN * 64 + 255) / 256, 256, 0, stream>>>(node_feat, hbf);
    init_x<<<(NN * 3 + 255) / 256, 256, 0, stream>>>(xyz, xA);
    hist_kernel<<<(NE + 255) / 256, 256, 0, stream>>>(dst, counts);
    scan_kernel<<<1, 1024, 0, stream>>>(counts, rowptr, counts);
    scatter_kernel<<<(NE + 255) / 256, 256, 0, stream>>>(src, dst, counts, srcS);

    // layer 0 (writes x for layer 1)
    edge2_kernel<true><<<1024, 256, 0, stream>>>(
        xA, hbf, rowptr, srcS,
        ew1, eb1, ew2, eb2, cw1, cb1, cw2, h_nb, xB);
    node_kernel<false><<<1024, 256, 0, stream>>>(
        hbf, h_nb, nw1, nb1, nw2, nb2, ln_g, ln_b, out_w, out_b, out);

    // layer 1 (x output dead -> no coord head; head fused into node kernel)
    edge2_kernel<false><<<1024, 256, 0, stream>>>(
        xB, hbf, rowptr, srcS,
        ew1 + 129 * 64, eb1 + 64, ew2 + 64 * 64, eb2 + 64,
        cw1 + 64 * 64, cb1 + 64, cw2 + 64, h_nb, nullptr);
    node_kernel<true><<<1024, 256, 0, stream>>>(
        hbf, h_nb, nw1 + 128 * 64, nb1 + 64, nw2 + 64 * 64, nb2 + 64,
        ln_g, ln_b, out_w, out_b, out);
}